// Round 11
// baseline (217.966 us; speedup 1.0000x reference)
//
#include <hip/hip_runtime.h>

typedef unsigned short ushort_t;
typedef short bf16x8 __attribute__((ext_vector_type(8)));
typedef float f32x4 __attribute__((ext_vector_type(4)));

#define MFMA16(a, b, c) __builtin_amdgcn_mfma_f32_16x16x32_bf16((a), (b), (c), 0, 0, 0)
#define DPP_ADD(v, ctrl) \
    ((v) + __int_as_float(__builtin_amdgcn_mov_dpp(__float_as_int(v), (ctrl), 0xF, 0xF, true)))
// Compiler-only memory barrier: staging writes (unsigned*/ushort*) and fragment
// reads (bf16x8*) are type-punned (TBAA no-alias); pin program order at phase
// boundaries. DS pipe is in-order per wave, so no s_waitcnt needed.
#define LDS_FENCE() asm volatile("" ::: "memory")

// QUARANTINE (do not reintroduce without disasm evidence):
//  - dual-buffered H2T with odd buffer aliased onto XA tok0 (R5/6/7/9 failures)
//  - fp32 bias tables in ws beyond NSETS KiB + MFMA C-init bias (R9/R10 failures)
// R8 (this base) is the verified-green configuration: post-add biases from
// global, single-buffer H2T @4096, pair-permuted QKV with dword XOR swizzle.

namespace {

constexpr int kB = 262144;

// ws B-fragment set bases (1 set = 64 lanes x 8 bf16 = 1 KiB)
constexpr int SET_W1 = 0;     // (100,23)  NT=7  KS=1
constexpr int SET_W2 = 7;     // (300,100) NT=20 KS=4
constexpr int SET_W3 = 87;    // (20,300)  NT=2  KS=10
constexpr int SET_WOBS = 107; // (20,17)   NT=2  KS=1
constexpr int SET_WACT = 109; // (20,6)    NT=2  KS=1, k shifted +17
constexpr int SET_WQKV = 111; // 3 x (60,20)  NT=4 KS=1
constexpr int SET_WO = 123;   // 3 x (20,20)  NT=2 KS=1
constexpr int SET_WF1 = 129;  // 3 x (128,20) NT=8 KS=1
constexpr int SET_WF2 = 153;  // 3 x (20,128) NT=2 KS=4
constexpr int NSETS = 177;

// per-wave LDS arena (ushort units). Arena = 4992 ushorts (9984 B).
constexpr int AR = 4992;
// XA:  [3 tok][16 rows][pitch 40]  x (pair-permuted bf16); token0 doubles as oa staging
// QKV: [3 tok][16 rows][pitch 64]  qkv, dword-XOR-swizzled; o overwrites in place
// ACT: [16][pitch 136]             h1 / ffn hidden — ALIASES QKV (disjoint in time)
// H2T: [16][pitch 40]              W2->W3 staging (aliases QKV tok2 tail)
constexpr int QKVu = 1920; // ushort base
constexpr int ACTu = 1920;
constexpr int H2Tu = 4096;

__device__ __forceinline__ unsigned pk_bf16(float lo, float hi) {
    unsigned r;
    asm("v_cvt_pk_bf16_f32 %0, %1, %2" : "=v"(r) : "v"(lo), "v"(hi));
    return r;
}
__device__ __forceinline__ float bf2f(ushort_t h) {
    return __uint_as_float(((unsigned)h) << 16);
}
__device__ __forceinline__ float red16(float v) {
    v = DPP_ADD(v, 0xB1);   // quad_perm [1,0,3,2]  (xor 1)
    v = DPP_ADD(v, 0x4E);   // quad_perm [2,3,0,1]  (xor 2)
    v = DPP_ADD(v, 0x124);  // row_ror:4
    v = DPP_ADD(v, 0x128);  // row_ror:8
    return v;
}
// feature f (0..63) -> ushort slot in a pair-permuted 64-wide row (no swizzle)
__device__ __forceinline__ int fslot(int f) {
    return ((f >> 5) << 5) + ((f & 15) << 1) + ((f >> 4) & 1);
}
// swizzled ushort offset within a QKV row; sw = (row&7)<<2
__device__ __forceinline__ int qoff(int f, int sw) {
    int s = fslot(f);
    return (((s >> 1) ^ sw) << 1) | (s & 1);
}

// ---------------- weight prep: fp32 -> bf16 B-fragments (permuted k) --------
__global__ void prep_weights(const float* __restrict__ W1, const float* __restrict__ W2,
                             const float* __restrict__ W3, const float* __restrict__ Wobs,
                             const float* __restrict__ Wact, const float* __restrict__ Wqkv,
                             const float* __restrict__ Wo, const float* __restrict__ Wf1,
                             const float* __restrict__ Wf2, ushort_t* __restrict__ ws) {
    int s = blockIdx.x, lane = threadIdx.x;
    const float* src;
    int Nout, Kin, kshift = 0, nt, ks;
    if (s < SET_W2) { src = W1; Nout = 100; Kin = 23; nt = s; ks = 0; }
    else if (s < SET_W3) { int t = s - SET_W2; src = W2; Nout = 300; Kin = 100; nt = t >> 2; ks = t & 3; }
    else if (s < SET_WOBS) { int t = s - SET_W3; src = W3; Nout = 20; Kin = 300; nt = t / 10; ks = t % 10; }
    else if (s < SET_WACT) { int t = s - SET_WOBS; src = Wobs; Nout = 20; Kin = 17; nt = t; ks = 0; }
    else if (s < SET_WQKV) { int t = s - SET_WACT; src = Wact; Nout = 20; Kin = 6; kshift = 17; nt = t; ks = 0; }
    else if (s < SET_WO) { int t = s - SET_WQKV; src = Wqkv + (t >> 2) * 1200; Nout = 60; Kin = 20; nt = t & 3; ks = 0; }
    else if (s < SET_WF1) { int t = s - SET_WO; src = Wo + (t >> 1) * 400; Nout = 20; Kin = 20; nt = t & 1; ks = 0; }
    else if (s < SET_WF2) { int t = s - SET_WF1; src = Wf1 + (t >> 3) * 2560; Nout = 128; Kin = 20; nt = t & 7; ks = 0; }
    else { int t = s - SET_WF2; src = Wf2 + (t >> 3) * 2560; Nout = 20; Kin = 128; int r = t & 7; nt = r >> 2; ks = r & 3; }

    int n = nt * 16 + (lane & 15);
    ushort_t h[8];
#pragma unroll
    for (int j = 0; j < 8; ++j) {
        int m = (lane >> 4) * 8 + j;             // k-slot within 32-span
        int kw = (m >> 1) + ((m & 1) << 4);      // pair-permuted feature within span
        int k = ks * 32 + kw;
        float v = 0.f;
        if (n < Nout && k >= kshift && k < kshift + Kin) v = src[n * Kin + (k - kshift)];
        unsigned u = __float_as_uint(v);
        h[j] = (ushort_t)((u + 0x7FFFu + ((u >> 16) & 1u)) >> 16);
    }
    uint4 pk;
    pk.x = (unsigned)h[0] | ((unsigned)h[1] << 16);
    pk.y = (unsigned)h[2] | ((unsigned)h[3] << 16);
    pk.z = (unsigned)h[4] | ((unsigned)h[5] << 16);
    pk.w = (unsigned)h[6] | ((unsigned)h[7] << 16);
    ((uint4*)ws)[s * 64 + lane] = pk;
}

// LN over 20 valid cols; y1 cols (16+r16)>=20 are exact zeros; ga1/ba1 pre-masked
__device__ __forceinline__ void ln20(f32x4& y0, f32x4& y1, float ga0, float ba0,
                                     float ga1, float ba1) {
#pragma unroll
    for (int j = 0; j < 4; ++j) {
        float s = red16(y0[j] + y1[j]);
        float s2 = red16(y0[j] * y0[j] + y1[j] * y1[j]);
        float mean = s * 0.05f;
        float var = s2 * 0.05f - mean * mean;
        float r = rsqrtf(var + 1e-5f);
        y0[j] = (y0[j] - mean) * r * ga0 + ba0;
        y1[j] = (y1[j] - mean) * r * ga1 + ba1;
    }
}

__global__ __launch_bounds__(128, 4)
void oat_mfma10(const float* __restrict__ obs, const float* __restrict__ act,
                const float* __restrict__ b1, const float* __restrict__ b2,
                const float* __restrict__ b3, const float* __restrict__ bobs,
                const float* __restrict__ bact, const float* __restrict__ pos,
                const float* __restrict__ bqkv, const float* __restrict__ bo,
                const float* __restrict__ g1, const float* __restrict__ be1,
                const float* __restrict__ bf1, const float* __restrict__ bf2,
                const float* __restrict__ g2, const float* __restrict__ be2,
                const float* __restrict__ Wfc, const float* __restrict__ bfc,
                const ushort_t* __restrict__ wsb, float* __restrict__ out) {
    __shared__ __align__(16) ushort_t sm[2 * AR];
    const int lane = threadIdx.x & 63, wid = threadIdx.x >> 6;
    const int r16 = lane & 15, kb = lane >> 4;
    const int row0 = blockIdx.x * 32 + wid * 16;
    ushort_t* S = sm + wid * AR;
    unsigned* SW = (unsigned*)S;
    const bf16x8* Bw = (const bf16x8*)wsb;
    const f32x4 zero = {0.f, 0.f, 0.f, 0.f};

    // ---- P0: stage oa (32 features: obs 0..16, act 17..22, pad) ------------
#pragma unroll
    for (int it = 0; it < 4; ++it) {
        int idx = it * 64 + lane;
        int r = idx >> 4, d = idx & 15;
        int gr = row0 + r;
        float lo = obs[gr * 17 + d];
        float hi = (d == 0) ? obs[gr * 17 + 16] : ((d <= 6) ? act[gr * 6 + (d - 1)] : 0.f);
        SW[r * 20 + d] = pk_bf16(lo, hi);
    }
    LDS_FENCE();  // oa stores -> aOA read

    // ---- P1: W1 (h1) + obs/act projections ---------------------------------
    f32x4 xf[3][2]; // [token][nt]
    bf16x8 aOA = *(const bf16x8*)(S + r16 * 40 + kb * 8);
    f32x4 c1[7];
    __builtin_amdgcn_s_setprio(1);
#pragma unroll
    for (int nt = 0; nt < 7; ++nt) c1[nt] = MFMA16(aOA, Bw[(SET_W1 + nt) * 64 + lane], zero);
    __builtin_amdgcn_s_setprio(0);
#pragma unroll
    for (int nt = 0; nt < 2; ++nt) {
        f32x4 po = MFMA16(aOA, Bw[(SET_WOBS + nt) * 64 + lane], zero);
        f32x4 pa = MFMA16(aOA, Bw[(SET_WACT + nt) * 64 + lane], zero);
        int col = nt * 16 + r16;
        bool v = col < 20;
        float aO = v ? (bobs[col] + pos[20 + col]) : 0.f;
        float aA = v ? (bact[col] + pos[40 + col]) : 0.f;
#pragma unroll
        for (int j = 0; j < 4; ++j) { po[j] += aO; pa[j] += aA; }
        xf[1][nt] = po;
        xf[2][nt] = pa;
    }
    // pack h1 -> ACT (4 spans of 32 feats; span3 hi-half = zeros)
#pragma unroll
    for (int m = 0; m < 4; ++m) {
        int cA = m * 32 + r16, cBc = m * 32 + 16 + r16;
        float ba = (cA < 100) ? b1[cA] : 0.f;
        float bb = (m < 3 && cBc < 100) ? b1[cBc] : 0.f;
#pragma unroll
        for (int j = 0; j < 4; ++j) {
            float lo = fmaxf(c1[2 * m][j] + ba, 0.f);
            float hi = (m < 3) ? fmaxf(c1[2 * m + 1][j] + bb, 0.f) : 0.f;
            SW[960 + (kb * 4 + j) * 68 + m * 16 + r16] = pk_bf16(lo, hi);
        }
    }
    LDS_FENCE();  // ACT stores -> aH1 reads
    bf16x8 aH1[4];
#pragma unroll
    for (int ks = 0; ks < 4; ++ks)
        aH1[ks] = *(const bf16x8*)(S + ACTu + r16 * 136 + ks * 32 + kb * 8);

    // ---- P2: W2 -> relu -> W3 ----------------------------------------------
    f32x4 mo[2];
    mo[0] = zero; mo[1] = zero;
#pragma unroll 1
    for (int np = 0; np < 10; ++np) {
        f32x4 cs[2];
        __builtin_amdgcn_s_setprio(1);
#pragma unroll
        for (int sub = 0; sub < 2; ++sub) {
            cs[sub] = zero;
#pragma unroll
            for (int ks = 0; ks < 4; ++ks)
                cs[sub] = MFMA16(aH1[ks], Bw[(SET_W2 + (np * 2 + sub) * 4 + ks) * 64 + lane], cs[sub]);
        }
        __builtin_amdgcn_s_setprio(0);
        int c0 = np * 32 + r16, c1c = np * 32 + 16 + r16;
        float b20 = (c0 < 300) ? b2[c0] : 0.f;
        float b21 = (c1c < 300) ? b2[c1c] : 0.f;
        LDS_FENCE();  // prev iter's aH2 read (buffer reuse, WAR) -> these stores
#pragma unroll
        for (int j = 0; j < 4; ++j)
            SW[2048 + (kb * 4 + j) * 20 + r16] =
                pk_bf16(fmaxf(cs[0][j] + b20, 0.f), fmaxf(cs[1][j] + b21, 0.f));
        LDS_FENCE();  // H2T stores -> aH2 read
        bf16x8 aH2 = *(const bf16x8*)(S + H2Tu + r16 * 40 + kb * 8);
#pragma unroll
        for (int nt2 = 0; nt2 < 2; ++nt2)
            mo[nt2] = MFMA16(aH2, Bw[(SET_W3 + nt2 * 10 + np) * 64 + lane], mo[nt2]);
    }

    // ---- P3: stack + pos; store x for all tokens ----------------------------
#pragma unroll
    for (int nt = 0; nt < 2; ++nt) {
        int col = nt * 16 + r16;
        float a0 = (col < 20) ? (b3[col] + pos[col]) : 0.f;
        f32x4 tt = mo[nt];
#pragma unroll
        for (int j = 0; j < 4; ++j) tt[j] += a0;
        xf[0][nt] = tt;
    }
#pragma unroll
    for (int t = 0; t < 3; ++t)
#pragma unroll
        for (int j = 0; j < 4; ++j)
            SW[t * 320 + (kb * 4 + j) * 20 + r16] = pk_bf16(xf[t][0][j], xf[t][1][j]);

    // ---- attention lane-address prep (lane-only, layer-invariant) -----------
    const int ah = lane & 3, ar = lane >> 2;
    const int swA = (ar & 7) << 2;
    int adr_q[5], adr_k[5], adr_v[5];
#pragma unroll
    for (int d = 0; d < 5; ++d) {
        adr_q[d] = qoff(ah * 5 + d, swA);
        adr_k[d] = qoff(20 + ah * 5 + d, swA);
        adr_v[d] = qoff(40 + ah * 5 + d, swA);
    }

    // ---- P4: 3 encoder layers ------------------------------------------------
#pragma unroll 1
    for (int l = 0; l < 3; ++l) {
        // hoisted per-layer biases / LN params
        float bq[4];
#pragma unroll
        for (int nt = 0; nt < 4; ++nt) {
            int col = nt * 16 + r16;
            bq[nt] = (col < 60) ? bqkv[l * 60 + col] : 0.f;
        }
        float bo0 = bo[l * 20 + r16];
        float bo1 = (r16 < 4) ? bo[l * 20 + 16 + r16] : 0.f;
        float fb0 = bf2[l * 20 + r16];
        float fb1 = (r16 < 4) ? bf2[l * 20 + 16 + r16] : 0.f;
        float g1a = g1[l * 20 + r16], e1a = be1[l * 20 + r16];
        float g1b = (r16 < 4) ? g1[l * 20 + 16 + r16] : 0.f;
        float e1b = (r16 < 4) ? be1[l * 20 + 16 + r16] : 0.f;
        float g2a = g2[l * 20 + r16], e2a = be2[l * 20 + r16];
        float g2b = (r16 < 4) ? g2[l * 20 + 16 + r16] : 0.f;
        float e2b = (r16 < 4) ? be2[l * 20 + 16 + r16] : 0.f;

        LDS_FENCE();  // x stores (P3 / prev-layer FFN) -> aX reads; ACT WAR
        // -- QKV GEMM (B-frags loaded once, 12 MFMAs in one window) --
        {
            bf16x8 bwq[4];
#pragma unroll
            for (int nt = 0; nt < 4; ++nt) bwq[nt] = Bw[(SET_WQKV + l * 4 + nt) * 64 + lane];
            __builtin_amdgcn_s_setprio(1);
#pragma unroll
            for (int t = 0; t < 3; ++t) {
                bf16x8 aX = *(const bf16x8*)(S + t * 640 + r16 * 40 + kb * 8);
                f32x4 cq[4];
#pragma unroll
                for (int nt = 0; nt < 4; ++nt) cq[nt] = MFMA16(aX, bwq[nt], zero);
#pragma unroll
                for (int j = 0; j < 4; ++j) {
                    int row = kb * 4 + j;
                    int rsw = (row & 7) << 2;
                    SW[960 + t * 512 + row * 32 + (r16 ^ rsw)] =
                        pk_bf16(cq[0][j] + bq[0], cq[1][j] + bq[1]);
                    SW[960 + t * 512 + row * 32 + ((16 + r16) ^ rsw)] =
                        pk_bf16(cq[2][j] + bq[2], cq[3][j] + bq[3]);
                }
            }
            __builtin_amdgcn_s_setprio(0);
        }
        LDS_FENCE();  // QKV pack stores -> attention ushort reads

        // -- attention: lane = (row ar, head ah); o overwrites q slots --
        {
            const int qb = QKVu + ar * 64;
            float q[3][5], kk[3][5], vv[3][5];
#pragma unroll
            for (int s = 0; s < 3; ++s)
#pragma unroll
                for (int d = 0; d < 5; ++d) {
                    q[s][d] = bf2f(S[qb + s * 1024 + adr_q[d]]);
                    kk[s][d] = bf2f(S[qb + s * 1024 + adr_k[d]]);
                    vv[s][d] = bf2f(S[qb + s * 1024 + adr_v[d]]);
                }
            float o[3][5];
#pragma unroll
            for (int s = 0; s < 3; ++s) {
                float sc[3];
#pragma unroll
                for (int t2 = 0; t2 < 3; ++t2) {
                    float a = 0.f;
#pragma unroll
                    for (int d = 0; d < 5; ++d) a = fmaf(q[s][d], kk[t2][d], a);
                    sc[t2] = a * 0.44721359549995793f;
                }
                float m = fmaxf(sc[0], fmaxf(sc[1], sc[2]));
                float e0 = __expf(sc[0] - m), e1 = __expf(sc[1] - m), e2 = __expf(sc[2] - m);
                float inv = 1.f / (e0 + e1 + e2);
                e0 *= inv; e1 *= inv; e2 *= inv;
#pragma unroll
                for (int d = 0; d < 5; ++d)
                    o[s][d] = fmaf(e0, vv[0][d], fmaf(e1, vv[1][d], e2 * vv[2][d]));
            }
#pragma unroll
            for (int s = 0; s < 3; ++s)
#pragma unroll
                for (int d = 0; d < 5; ++d)
                    S[qb + s * 1024 + adr_q[d]] = (ushort_t)pk_bf16(o[s][d], o[s][d]);
        }
        LDS_FENCE();  // o stores -> aO reads

        // -- Wo + residual + LN1 for ALL tokens (then QKV region is dead) --
        {
            bf16x8 bw_o0 = Bw[(SET_WO + l * 2 + 0) * 64 + lane];
            bf16x8 bw_o1 = Bw[(SET_WO + l * 2 + 1) * 64 + lane];
            int rsw = (r16 & 7) << 2;
#pragma unroll
            for (int t = 0; t < 3; ++t) {
                bf16x8 aO = *(const bf16x8*)(S + QKVu + t * 1024 + r16 * 64 + (((kb * 4) ^ rsw) << 1));
                f32x4 cw0 = MFMA16(aO, bw_o0, zero);
                f32x4 cw1 = MFMA16(aO, bw_o1, zero);
                f32x4 y0 = xf[t][0], y1 = xf[t][1];
#pragma unroll
                for (int j = 0; j < 4; ++j) { y0[j] += cw0[j] + bo0; y1[j] += cw1[j] + bo1; }
                ln20(y0, y1, g1a, e1a, g1b, e1b);
                xf[t][0] = y0; xf[t][1] = y1;
#pragma unroll
                for (int j = 0; j < 4; ++j)
                    SW[t * 320 + (kb * 4 + j) * 20 + r16] = pk_bf16(y0[j], y1[j]);
            }
        }

        // -- FFN all tokens (hidden aliases dead QKV region), fully unrolled --
#pragma unroll
        for (int t = 0; t < 3; ++t) {
            LDS_FENCE();  // x stores -> aX read; prev-t aF reads (ACT WAR) -> stores
            bf16x8 aX = *(const bf16x8*)(S + t * 640 + r16 * 40 + kb * 8);
            // FFN1: pack hidden in span pairs
            __builtin_amdgcn_s_setprio(1);
#pragma unroll
            for (int m = 0; m < 4; ++m) {
                bf16x8 bwa = Bw[(SET_WF1 + l * 8 + 2 * m) * 64 + lane];
                bf16x8 bwb = Bw[(SET_WF1 + l * 8 + 2 * m + 1) * 64 + lane];
                float f0 = bf1[l * 128 + m * 32 + r16];
                float f1 = bf1[l * 128 + m * 32 + 16 + r16];
                f32x4 ca = MFMA16(aX, bwa, zero);
                f32x4 cb = MFMA16(aX, bwb, zero);
#pragma unroll
                for (int j = 0; j < 4; ++j)
                    SW[960 + (kb * 4 + j) * 68 + m * 16 + r16] =
                        pk_bf16(fmaxf(ca[j] + f0, 0.f), fmaxf(cb[j] + f1, 0.f));
            }
            __builtin_amdgcn_s_setprio(0);
            LDS_FENCE();  // ACT stores -> aF reads
            // FFN2
            f32x4 c2[2];
            c2[0] = zero; c2[1] = zero;
            __builtin_amdgcn_s_setprio(1);
#pragma unroll
            for (int ks = 0; ks < 4; ++ks) {
                bf16x8 aF = *(const bf16x8*)(S + ACTu + r16 * 136 + ks * 32 + kb * 8);
                c2[0] = MFMA16(aF, Bw[(SET_WF2 + l * 8 + ks) * 64 + lane], c2[0]);
                c2[1] = MFMA16(aF, Bw[(SET_WF2 + l * 8 + 4 + ks) * 64 + lane], c2[1]);
            }
            __builtin_amdgcn_s_setprio(0);
            f32x4 z0 = xf[t][0], z1 = xf[t][1];
#pragma unroll
            for (int j = 0; j < 4; ++j) { z0[j] += c2[0][j] + fb0; z1[j] += c2[1][j] + fb1; }
            ln20(z0, z1, g2a, e2a, g2b, e2b);
            xf[t][0] = z0; xf[t][1] = z1;
            if (l != 2) {  // final layer: x only consumed from registers in P5
#pragma unroll
                for (int j = 0; j < 4; ++j)
                    SW[t * 320 + (kb * 4 + j) * 20 + r16] = pk_bf16(z0[j], z1[j]);
            }
        }
    }

    // ---- P5: head (B,60) @ Wfc^T + bfc --------------------------------------
    f32x4 p = zero;
#pragma unroll
    for (int t = 0; t < 3; ++t) {
        float w0 = Wfc[t * 20 + r16];
        float w1 = (r16 < 4) ? Wfc[t * 20 + 16 + r16] : 0.f;
#pragma unroll
        for (int j = 0; j < 4; ++j)
            p[j] = fmaf(xf[t][0][j], w0, fmaf(xf[t][1][j], w1, p[j]));
    }
#pragma unroll
    for (int j = 0; j < 4; ++j) p[j] = red16(p[j]);
    if (r16 < 4) {
        float v = (r16 == 0) ? p[0] : (r16 == 1) ? p[1] : (r16 == 2) ? p[2] : p[3];
        out[row0 + kb * 4 + r16] = v + bfc[0];
    }
}

} // namespace

extern "C" void kernel_launch(void* const* d_in, const int* in_sizes, int n_in,
                              void* d_out, int out_size, void* d_ws, size_t ws_size,
                              hipStream_t stream) {
    (void)in_sizes; (void)n_in; (void)out_size; (void)ws_size;
    const float* obs  = (const float*)d_in[0];
    const float* act  = (const float*)d_in[1];
    const float* W1   = (const float*)d_in[2];
    const float* b1   = (const float*)d_in[3];
    const float* W2   = (const float*)d_in[4];
    const float* b2   = (const float*)d_in[5];
    const float* W3   = (const float*)d_in[6];
    const float* b3   = (const float*)d_in[7];
    const float* Wobs = (const float*)d_in[8];
    const float* bobs = (const float*)d_in[9];
    const float* Wact = (const float*)d_in[10];
    const float* bact = (const float*)d_in[11];
    const float* pos  = (const float*)d_in[12];
    const float* Wqkv = (const float*)d_in[13];
    const float* bqkv = (const float*)d_in[14];
    const float* Wo   = (const float*)d_in[15];
    const float* bo   = (const float*)d_in[16];
    const float* g1   = (const float*)d_in[17];
    const float* be1  = (const float*)d_in[18];
    const float* Wf1  = (const float*)d_in[19];
    const float* bf1  = (const float*)d_in[20];
    const float* Wf2  = (const float*)d_in[21];
    const float* bf2  = (const float*)d_in[22];
    const float* g2   = (const float*)d_in[23];
    const float* be2  = (const float*)d_in[24];
    const float* Wfc  = (const float*)d_in[25];
    const float* bfc  = (const float*)d_in[26];

    ushort_t* wsb = (ushort_t*)d_ws;

    hipLaunchKernelGGL(prep_weights, dim3(NSETS), dim3(64), 0, stream,
                       W1, W2, W3, Wobs, Wact, Wqkv, Wo, Wf1, Wf2, wsb);
    hipLaunchKernelGGL(oat_mfma10, dim3(kB / 32), dim3(128), 0, stream,
                       obs, act, b1, b2, b3, bobs, bact, pos, bqkv, bo,
                       g1, be1, bf1, bf2, g2, be2, Wfc, bfc, wsb, (float*)d_out);
}

// Round 12
// 213.201 us; speedup vs baseline: 1.0223x; 1.0223x over previous
//
#include <hip/hip_runtime.h>

typedef unsigned short ushort_t;
typedef short bf16x8 __attribute__((ext_vector_type(8)));
typedef float f32x4 __attribute__((ext_vector_type(4)));

#define MFMA16(a, b, c) __builtin_amdgcn_mfma_f32_16x16x32_bf16((a), (b), (c), 0, 0, 0)
#define DPP_ADD(v, ctrl) \
    ((v) + __int_as_float(__builtin_amdgcn_mov_dpp(__float_as_int(v), (ctrl), 0xF, 0xF, true)))
// Compiler-only memory barrier: staging writes (unsigned*/ushort*) and fragment
// reads (bf16x8*) are type-punned (TBAA no-alias); pin program order at phase
// boundaries. DS pipe is in-order per wave, so no s_waitcnt needed.
#define LDS_FENCE() asm volatile("" ::: "memory")

// QUARANTINE (do not reintroduce without disasm evidence):
//  - dual-buffered H2T with odd buffer aliased onto XA tok0 (R5/6/7/9 failures)
//  - fp32 bias tables in ws beyond NSETS KiB + MFMA C-init bias (R9/R10 failures)
//  - s_setprio around MFMA clusters (R11: −5% — homogeneous waves, no role-split)
// R8 base is the verified-green configuration: post-add biases from global,
// single-buffer H2T @4096, pair-permuted QKV with dword XOR swizzle.

namespace {

constexpr int kB = 262144;

// ws B-fragment set bases (1 set = 64 lanes x 8 bf16 = 1 KiB)
constexpr int SET_W1 = 0;     // (100,23)  NT=7  KS=1
constexpr int SET_W2 = 7;     // (300,100) NT=20 KS=4
constexpr int SET_W3 = 87;    // (20,300)  NT=2  KS=10
constexpr int SET_WOBS = 107; // (20,17)   NT=2  KS=1
constexpr int SET_WACT = 109; // (20,6)    NT=2  KS=1, k shifted +17
constexpr int SET_WQKV = 111; // 3 x (60,20)  NT=4 KS=1
constexpr int SET_WO = 123;   // 3 x (20,20)  NT=2 KS=1
constexpr int SET_WF1 = 129;  // 3 x (128,20) NT=8 KS=1
constexpr int SET_WF2 = 153;  // 3 x (20,128) NT=2 KS=4
constexpr int NSETS = 177;

// per-wave LDS arena (ushort units). Arena = 4992 ushorts (9984 B).
constexpr int AR = 4992;
// XA:  [3 tok][16 rows][pitch 40]  x (pair-permuted bf16); token0 doubles as oa staging
// QKV: [3 tok][16 rows][pitch 64]  qkv, dword-XOR-swizzled; o overwrites in place
// ACT: [16][pitch 136]             h1 / ffn hidden — ALIASES QKV (disjoint in time)
// H2T: [16][pitch 40]              W2->W3 staging (aliases QKV tok2 tail)
constexpr int QKVu = 1920; // ushort base
constexpr int ACTu = 1920;
constexpr int H2Tu = 4096;

__device__ __forceinline__ unsigned pk_bf16(float lo, float hi) {
    unsigned r;
    asm("v_cvt_pk_bf16_f32 %0, %1, %2" : "=v"(r) : "v"(lo), "v"(hi));
    return r;
}
__device__ __forceinline__ float bf2f(ushort_t h) {
    return __uint_as_float(((unsigned)h) << 16);
}
__device__ __forceinline__ float red16(float v) {
    v = DPP_ADD(v, 0xB1);   // quad_perm [1,0,3,2]  (xor 1)
    v = DPP_ADD(v, 0x4E);   // quad_perm [2,3,0,1]  (xor 2)
    v = DPP_ADD(v, 0x124);  // row_ror:4
    v = DPP_ADD(v, 0x128);  // row_ror:8
    return v;
}
// feature f (0..63) -> ushort slot in a pair-permuted 64-wide row (no swizzle)
__device__ __forceinline__ int fslot(int f) {
    return ((f >> 5) << 5) + ((f & 15) << 1) + ((f >> 4) & 1);
}
// swizzled ushort offset within a QKV row; sw = (row&7)<<2
__device__ __forceinline__ int qoff(int f, int sw) {
    int s = fslot(f);
    return (((s >> 1) ^ sw) << 1) | (s & 1);
}

// ---------------- weight prep: fp32 -> bf16 B-fragments (permuted k) --------
__global__ void prep_weights(const float* __restrict__ W1, const float* __restrict__ W2,
                             const float* __restrict__ W3, const float* __restrict__ Wobs,
                             const float* __restrict__ Wact, const float* __restrict__ Wqkv,
                             const float* __restrict__ Wo, const float* __restrict__ Wf1,
                             const float* __restrict__ Wf2, ushort_t* __restrict__ ws) {
    int s = blockIdx.x, lane = threadIdx.x;
    const float* src;
    int Nout, Kin, kshift = 0, nt, ks;
    if (s < SET_W2) { src = W1; Nout = 100; Kin = 23; nt = s; ks = 0; }
    else if (s < SET_W3) { int t = s - SET_W2; src = W2; Nout = 300; Kin = 100; nt = t >> 2; ks = t & 3; }
    else if (s < SET_WOBS) { int t = s - SET_W3; src = W3; Nout = 20; Kin = 300; nt = t / 10; ks = t % 10; }
    else if (s < SET_WACT) { int t = s - SET_WOBS; src = Wobs; Nout = 20; Kin = 17; nt = t; ks = 0; }
    else if (s < SET_WQKV) { int t = s - SET_WACT; src = Wact; Nout = 20; Kin = 6; kshift = 17; nt = t; ks = 0; }
    else if (s < SET_WO) { int t = s - SET_WQKV; src = Wqkv + (t >> 2) * 1200; Nout = 60; Kin = 20; nt = t & 3; ks = 0; }
    else if (s < SET_WF1) { int t = s - SET_WO; src = Wo + (t >> 1) * 400; Nout = 20; Kin = 20; nt = t & 1; ks = 0; }
    else if (s < SET_WF2) { int t = s - SET_WF1; src = Wf1 + (t >> 3) * 2560; Nout = 128; Kin = 20; nt = t & 7; ks = 0; }
    else { int t = s - SET_WF2; src = Wf2 + (t >> 3) * 2560; Nout = 20; Kin = 128; int r = t & 7; nt = r >> 2; ks = r & 3; }

    int n = nt * 16 + (lane & 15);
    ushort_t h[8];
#pragma unroll
    for (int j = 0; j < 8; ++j) {
        int m = (lane >> 4) * 8 + j;             // k-slot within 32-span
        int kw = (m >> 1) + ((m & 1) << 4);      // pair-permuted feature within span
        int k = ks * 32 + kw;
        float v = 0.f;
        if (n < Nout && k >= kshift && k < kshift + Kin) v = src[n * Kin + (k - kshift)];
        unsigned u = __float_as_uint(v);
        h[j] = (ushort_t)((u + 0x7FFFu + ((u >> 16) & 1u)) >> 16);
    }
    uint4 pk;
    pk.x = (unsigned)h[0] | ((unsigned)h[1] << 16);
    pk.y = (unsigned)h[2] | ((unsigned)h[3] << 16);
    pk.z = (unsigned)h[4] | ((unsigned)h[5] << 16);
    pk.w = (unsigned)h[6] | ((unsigned)h[7] << 16);
    ((uint4*)ws)[s * 64 + lane] = pk;
}

// LN over 20 valid cols; y1 cols (16+r16)>=20 are exact zeros; ga1/ba1 pre-masked
__device__ __forceinline__ void ln20(f32x4& y0, f32x4& y1, float ga0, float ba0,
                                     float ga1, float ba1) {
#pragma unroll
    for (int j = 0; j < 4; ++j) {
        float s = red16(y0[j] + y1[j]);
        float s2 = red16(y0[j] * y0[j] + y1[j] * y1[j]);
        float mean = s * 0.05f;
        float var = s2 * 0.05f - mean * mean;
        float r = rsqrtf(var + 1e-5f);
        y0[j] = (y0[j] - mean) * r * ga0 + ba0;
        y1[j] = (y1[j] - mean) * r * ga1 + ba1;
    }
}

__global__ __launch_bounds__(128, 4)
void oat_mfma11(const float* __restrict__ obs, const float* __restrict__ act,
                const float* __restrict__ b1, const float* __restrict__ b2,
                const float* __restrict__ b3, const float* __restrict__ bobs,
                const float* __restrict__ bact, const float* __restrict__ pos,
                const float* __restrict__ bqkv, const float* __restrict__ bo,
                const float* __restrict__ g1, const float* __restrict__ be1,
                const float* __restrict__ bf1, const float* __restrict__ bf2,
                const float* __restrict__ g2, const float* __restrict__ be2,
                const float* __restrict__ Wfc, const float* __restrict__ bfc,
                const ushort_t* __restrict__ wsb, float* __restrict__ out) {
    __shared__ __align__(16) ushort_t sm[2 * AR];
    const int lane = threadIdx.x & 63, wid = threadIdx.x >> 6;
    const int r16 = lane & 15, kb = lane >> 4;
    const int row0 = blockIdx.x * 32 + wid * 16;
    ushort_t* S = sm + wid * AR;
    unsigned* SW = (unsigned*)S;
    const bf16x8* Bw = (const bf16x8*)wsb;
    const f32x4 zero = {0.f, 0.f, 0.f, 0.f};

    // ---- P0: stage oa (32 features: obs 0..16, act 17..22, pad) ------------
#pragma unroll
    for (int it = 0; it < 4; ++it) {
        int idx = it * 64 + lane;
        int r = idx >> 4, d = idx & 15;
        int gr = row0 + r;
        float lo = obs[gr * 17 + d];
        float hi = (d == 0) ? obs[gr * 17 + 16] : ((d <= 6) ? act[gr * 6 + (d - 1)] : 0.f);
        SW[r * 20 + d] = pk_bf16(lo, hi);
    }
    LDS_FENCE();  // oa stores -> aOA read

    // ---- P1: W1 (h1) + obs/act projections ---------------------------------
    f32x4 xf[3][2]; // [token][nt]
    bf16x8 aOA = *(const bf16x8*)(S + r16 * 40 + kb * 8);
    f32x4 c1[7];
#pragma unroll
    for (int nt = 0; nt < 7; ++nt) c1[nt] = MFMA16(aOA, Bw[(SET_W1 + nt) * 64 + lane], zero);
#pragma unroll
    for (int nt = 0; nt < 2; ++nt) {
        f32x4 po = MFMA16(aOA, Bw[(SET_WOBS + nt) * 64 + lane], zero);
        f32x4 pa = MFMA16(aOA, Bw[(SET_WACT + nt) * 64 + lane], zero);
        int col = nt * 16 + r16;
        bool v = col < 20;
        float aO = v ? (bobs[col] + pos[20 + col]) : 0.f;
        float aA = v ? (bact[col] + pos[40 + col]) : 0.f;
#pragma unroll
        for (int j = 0; j < 4; ++j) { po[j] += aO; pa[j] += aA; }
        xf[1][nt] = po;
        xf[2][nt] = pa;
    }
    // pack h1 -> ACT (4 spans of 32 feats; span3 hi-half = zeros)
#pragma unroll
    for (int m = 0; m < 4; ++m) {
        int cA = m * 32 + r16, cBc = m * 32 + 16 + r16;
        float ba = (cA < 100) ? b1[cA] : 0.f;
        float bb = (m < 3 && cBc < 100) ? b1[cBc] : 0.f;
#pragma unroll
        for (int j = 0; j < 4; ++j) {
            float lo = fmaxf(c1[2 * m][j] + ba, 0.f);
            float hi = (m < 3) ? fmaxf(c1[2 * m + 1][j] + bb, 0.f) : 0.f;
            SW[960 + (kb * 4 + j) * 68 + m * 16 + r16] = pk_bf16(lo, hi);
        }
    }
    LDS_FENCE();  // ACT stores -> aH1 reads
    bf16x8 aH1[4];
#pragma unroll
    for (int ks = 0; ks < 4; ++ks)
        aH1[ks] = *(const bf16x8*)(S + ACTu + r16 * 136 + ks * 32 + kb * 8);

    // ---- P2: W2 -> relu -> W3 ----------------------------------------------
    f32x4 mo[2];
    mo[0] = zero; mo[1] = zero;
#pragma unroll 1
    for (int np = 0; np < 10; ++np) {
        f32x4 cs[2];
#pragma unroll
        for (int sub = 0; sub < 2; ++sub) {
            cs[sub] = zero;
#pragma unroll
            for (int ks = 0; ks < 4; ++ks)
                cs[sub] = MFMA16(aH1[ks], Bw[(SET_W2 + (np * 2 + sub) * 4 + ks) * 64 + lane], cs[sub]);
        }
        int c0 = np * 32 + r16, c1c = np * 32 + 16 + r16;
        float b20 = (c0 < 300) ? b2[c0] : 0.f;
        float b21 = (c1c < 300) ? b2[c1c] : 0.f;
        LDS_FENCE();  // prev iter's aH2 read (buffer reuse, WAR) -> these stores
#pragma unroll
        for (int j = 0; j < 4; ++j)
            SW[2048 + (kb * 4 + j) * 20 + r16] =
                pk_bf16(fmaxf(cs[0][j] + b20, 0.f), fmaxf(cs[1][j] + b21, 0.f));
        LDS_FENCE();  // H2T stores -> aH2 read
        bf16x8 aH2 = *(const bf16x8*)(S + H2Tu + r16 * 40 + kb * 8);
#pragma unroll
        for (int nt2 = 0; nt2 < 2; ++nt2)
            mo[nt2] = MFMA16(aH2, Bw[(SET_W3 + nt2 * 10 + np) * 64 + lane], mo[nt2]);
    }

    // ---- P3: stack + pos; store x for all tokens ----------------------------
#pragma unroll
    for (int nt = 0; nt < 2; ++nt) {
        int col = nt * 16 + r16;
        float a0 = (col < 20) ? (b3[col] + pos[col]) : 0.f;
        f32x4 tt = mo[nt];
#pragma unroll
        for (int j = 0; j < 4; ++j) tt[j] += a0;
        xf[0][nt] = tt;
    }
#pragma unroll
    for (int t = 0; t < 3; ++t)
#pragma unroll
        for (int j = 0; j < 4; ++j)
            SW[t * 320 + (kb * 4 + j) * 20 + r16] = pk_bf16(xf[t][0][j], xf[t][1][j]);

    // ---- attention lane-address prep (lane-only, layer-invariant) -----------
    const int ah = lane & 3, ar = lane >> 2;
    const int swA = (ar & 7) << 2;
    int adr_q[5], adr_k[5], adr_v[5];
#pragma unroll
    for (int d = 0; d < 5; ++d) {
        adr_q[d] = qoff(ah * 5 + d, swA);
        adr_k[d] = qoff(20 + ah * 5 + d, swA);
        adr_v[d] = qoff(40 + ah * 5 + d, swA);
    }

    // ---- P4: 3 encoder layers ------------------------------------------------
#pragma unroll 1
    for (int l = 0; l < 3; ++l) {
        // hoisted per-layer biases / LN params
        float bq[4];
#pragma unroll
        for (int nt = 0; nt < 4; ++nt) {
            int col = nt * 16 + r16;
            bq[nt] = (col < 60) ? bqkv[l * 60 + col] : 0.f;
        }
        float bo0 = bo[l * 20 + r16];
        float bo1 = (r16 < 4) ? bo[l * 20 + 16 + r16] : 0.f;
        float fb0 = bf2[l * 20 + r16];
        float fb1 = (r16 < 4) ? bf2[l * 20 + 16 + r16] : 0.f;
        float g1a = g1[l * 20 + r16], e1a = be1[l * 20 + r16];
        float g1b = (r16 < 4) ? g1[l * 20 + 16 + r16] : 0.f;
        float e1b = (r16 < 4) ? be1[l * 20 + 16 + r16] : 0.f;
        float g2a = g2[l * 20 + r16], e2a = be2[l * 20 + r16];
        float g2b = (r16 < 4) ? g2[l * 20 + 16 + r16] : 0.f;
        float e2b = (r16 < 4) ? be2[l * 20 + 16 + r16] : 0.f;

        LDS_FENCE();  // x stores (P3 / prev-layer FFN) -> aX reads; ACT WAR
        // -- QKV GEMM (B-frags loaded once, 12 MFMAs in one window) --
        {
            bf16x8 bwq[4];
#pragma unroll
            for (int nt = 0; nt < 4; ++nt) bwq[nt] = Bw[(SET_WQKV + l * 4 + nt) * 64 + lane];
#pragma unroll
            for (int t = 0; t < 3; ++t) {
                bf16x8 aX = *(const bf16x8*)(S + t * 640 + r16 * 40 + kb * 8);
                f32x4 cq[4];
#pragma unroll
                for (int nt = 0; nt < 4; ++nt) cq[nt] = MFMA16(aX, bwq[nt], zero);
#pragma unroll
                for (int j = 0; j < 4; ++j) {
                    int row = kb * 4 + j;
                    int rsw = (row & 7) << 2;
                    SW[960 + t * 512 + row * 32 + (r16 ^ rsw)] =
                        pk_bf16(cq[0][j] + bq[0], cq[1][j] + bq[1]);
                    SW[960 + t * 512 + row * 32 + ((16 + r16) ^ rsw)] =
                        pk_bf16(cq[2][j] + bq[2], cq[3][j] + bq[3]);
                }
            }
        }
        LDS_FENCE();  // QKV pack stores -> attention ushort reads

        // -- attention: lane = (row ar, head ah); o overwrites q slots --
        {
            const int qb = QKVu + ar * 64;
            float q[3][5], kk[3][5], vv[3][5];
#pragma unroll
            for (int s = 0; s < 3; ++s)
#pragma unroll
                for (int d = 0; d < 5; ++d) {
                    q[s][d] = bf2f(S[qb + s * 1024 + adr_q[d]]);
                    kk[s][d] = bf2f(S[qb + s * 1024 + adr_k[d]]);
                    vv[s][d] = bf2f(S[qb + s * 1024 + adr_v[d]]);
                }
            float o[3][5];
#pragma unroll
            for (int s = 0; s < 3; ++s) {
                float sc[3];
#pragma unroll
                for (int t2 = 0; t2 < 3; ++t2) {
                    float a = 0.f;
#pragma unroll
                    for (int d = 0; d < 5; ++d) a = fmaf(q[s][d], kk[t2][d], a);
                    sc[t2] = a * 0.44721359549995793f;
                }
                float m = fmaxf(sc[0], fmaxf(sc[1], sc[2]));
                float e0 = __expf(sc[0] - m), e1 = __expf(sc[1] - m), e2 = __expf(sc[2] - m);
                float inv = 1.f / (e0 + e1 + e2);
                e0 *= inv; e1 *= inv; e2 *= inv;
#pragma unroll
                for (int d = 0; d < 5; ++d)
                    o[s][d] = fmaf(e0, vv[0][d], fmaf(e1, vv[1][d], e2 * vv[2][d]));
            }
#pragma unroll
            for (int s = 0; s < 3; ++s)
#pragma unroll
                for (int d = 0; d < 5; ++d)
                    S[qb + s * 1024 + adr_q[d]] = (ushort_t)pk_bf16(o[s][d], o[s][d]);
        }
        LDS_FENCE();  // o stores -> aO reads

        // -- Wo + residual + LN1 for ALL tokens (then QKV region is dead) --
        {
            bf16x8 bw_o0 = Bw[(SET_WO + l * 2 + 0) * 64 + lane];
            bf16x8 bw_o1 = Bw[(SET_WO + l * 2 + 1) * 64 + lane];
            int rsw = (r16 & 7) << 2;
#pragma unroll
            for (int t = 0; t < 3; ++t) {
                bf16x8 aO = *(const bf16x8*)(S + QKVu + t * 1024 + r16 * 64 + (((kb * 4) ^ rsw) << 1));
                f32x4 cw0 = MFMA16(aO, bw_o0, zero);
                f32x4 cw1 = MFMA16(aO, bw_o1, zero);
                f32x4 y0 = xf[t][0], y1 = xf[t][1];
#pragma unroll
                for (int j = 0; j < 4; ++j) { y0[j] += cw0[j] + bo0; y1[j] += cw1[j] + bo1; }
                ln20(y0, y1, g1a, e1a, g1b, e1b);
                xf[t][0] = y0; xf[t][1] = y1;
#pragma unroll
                for (int j = 0; j < 4; ++j)
                    SW[t * 320 + (kb * 4 + j) * 20 + r16] = pk_bf16(y0[j], y1[j]);
            }
        }

        // -- FFN all tokens (hidden aliases dead QKV region), fully unrolled --
#pragma unroll
        for (int t = 0; t < 3; ++t) {
            LDS_FENCE();  // x stores -> aX read; prev-t aF reads (ACT WAR) -> stores
            bf16x8 aX = *(const bf16x8*)(S + t * 640 + r16 * 40 + kb * 8);
            // FFN1: pack hidden in span pairs
#pragma unroll
            for (int m = 0; m < 4; ++m) {
                bf16x8 bwa = Bw[(SET_WF1 + l * 8 + 2 * m) * 64 + lane];
                bf16x8 bwb = Bw[(SET_WF1 + l * 8 + 2 * m + 1) * 64 + lane];
                float f0 = bf1[l * 128 + m * 32 + r16];
                float f1 = bf1[l * 128 + m * 32 + 16 + r16];
                f32x4 ca = MFMA16(aX, bwa, zero);
                f32x4 cb = MFMA16(aX, bwb, zero);
#pragma unroll
                for (int j = 0; j < 4; ++j)
                    SW[960 + (kb * 4 + j) * 68 + m * 16 + r16] =
                        pk_bf16(fmaxf(ca[j] + f0, 0.f), fmaxf(cb[j] + f1, 0.f));
            }
            LDS_FENCE();  // ACT stores -> aF reads
            // FFN2
            f32x4 c2[2];
            c2[0] = zero; c2[1] = zero;
#pragma unroll
            for (int ks = 0; ks < 4; ++ks) {
                bf16x8 aF = *(const bf16x8*)(S + ACTu + r16 * 136 + ks * 32 + kb * 8);
                c2[0] = MFMA16(aF, Bw[(SET_WF2 + l * 8 + ks) * 64 + lane], c2[0]);
                c2[1] = MFMA16(aF, Bw[(SET_WF2 + l * 8 + 4 + ks) * 64 + lane], c2[1]);
            }
            f32x4 z0 = xf[t][0], z1 = xf[t][1];
#pragma unroll
            for (int j = 0; j < 4; ++j) { z0[j] += c2[0][j] + fb0; z1[j] += c2[1][j] + fb1; }
            ln20(z0, z1, g2a, e2a, g2b, e2b);
            xf[t][0] = z0; xf[t][1] = z1;
            if (l != 2) {  // final layer: x only consumed from registers in P5
#pragma unroll
                for (int j = 0; j < 4; ++j)
                    SW[t * 320 + (kb * 4 + j) * 20 + r16] = pk_bf16(z0[j], z1[j]);
            }
        }
    }

    // ---- P5: head (B,60) @ Wfc^T + bfc --------------------------------------
    f32x4 p = zero;
#pragma unroll
    for (int t = 0; t < 3; ++t) {
        float w0 = Wfc[t * 20 + r16];
        float w1 = (r16 < 4) ? Wfc[t * 20 + 16 + r16] : 0.f;
#pragma unroll
        for (int j = 0; j < 4; ++j)
            p[j] = fmaf(xf[t][0][j], w0, fmaf(xf[t][1][j], w1, p[j]));
    }
#pragma unroll
    for (int j = 0; j < 4; ++j) p[j] = red16(p[j]);
    if (r16 < 4) {
        float v = (r16 == 0) ? p[0] : (r16 == 1) ? p[1] : (r16 == 2) ? p[2] : p[3];
        out[row0 + kb * 4 + r16] = v + bfc[0];
    }
}

} // namespace

extern "C" void kernel_launch(void* const* d_in, const int* in_sizes, int n_in,
                              void* d_out, int out_size, void* d_ws, size_t ws_size,
                              hipStream_t stream) {
    (void)in_sizes; (void)n_in; (void)out_size; (void)ws_size;
    const float* obs  = (const float*)d_in[0];
    const float* act  = (const float*)d_in[1];
    const float* W1   = (const float*)d_in[2];
    const float* b1   = (const float*)d_in[3];
    const float* W2   = (const float*)d_in[4];
    const float* b2   = (const float*)d_in[5];
    const float* W3   = (const float*)d_in[6];
    const float* b3   = (const float*)d_in[7];
    const float* Wobs = (const float*)d_in[8];
    const float* bobs = (const float*)d_in[9];
    const float* Wact = (const float*)d_in[10];
    const float* bact = (const float*)d_in[11];
    const float* pos  = (const float*)d_in[12];
    const float* Wqkv = (const float*)d_in[13];
    const float* bqkv = (const float*)d_in[14];
    const float* Wo   = (const float*)d_in[15];
    const float* bo   = (const float*)d_in[16];
    const float* g1   = (const float*)d_in[17];
    const float* be1  = (const float*)d_in[18];
    const float* Wf1  = (const float*)d_in[19];
    const float* bf1  = (const float*)d_in[20];
    const float* Wf2  = (const float*)d_in[21];
    const float* bf2  = (const float*)d_in[22];
    const float* g2   = (const float*)d_in[23];
    const float* be2  = (const float*)d_in[24];
    const float* Wfc  = (const float*)d_in[25];
    const float* bfc  = (const float*)d_in[26];

    ushort_t* wsb = (ushort_t*)d_ws;

    hipLaunchKernelGGL(prep_weights, dim3(NSETS), dim3(64), 0, stream,
                       W1, W2, W3, Wobs, Wact, Wqkv, Wo, Wf1, Wf2, wsb);
    hipLaunchKernelGGL(oat_mfma11, dim3(kB / 32), dim3(128), 0, stream,
                       obs, act, b1, b2, b3, bobs, bact, pos, bqkv, bo,
                       g1, be1, bf1, bf2, g2, be2, Wfc, bfc, wsb, (float*)d_out);
}

// Round 13
// 206.749 us; speedup vs baseline: 1.0543x; 1.0312x over previous
//
#include <hip/hip_runtime.h>

typedef unsigned short ushort_t;
typedef short bf16x8 __attribute__((ext_vector_type(8)));
typedef float f32x4 __attribute__((ext_vector_type(4)));

#define MFMA16(a, b, c) __builtin_amdgcn_mfma_f32_16x16x32_bf16((a), (b), (c), 0, 0, 0)
#define DPP_ADD(v, ctrl) \
    ((v) + __int_as_float(__builtin_amdgcn_mov_dpp(__float_as_int(v), (ctrl), 0xF, 0xF, true)))
// Compiler-only memory barrier: staging writes (unsigned*/ushort*) and fragment
// reads (bf16x8*) are type-punned (TBAA no-alias); pin program order at phase
// boundaries. DS pipe is in-order per wave, so no s_waitcnt needed.
#define LDS_FENCE() asm volatile("" ::: "memory")

// QUARANTINE / REGRESSION LOG (do not reintroduce without disasm evidence):
//  - dual-buffered H2T, odd buffer on XA tok0 (R5/6/7/9: correctness failures)
//  - fp32 bias tables past NSETS KiB + MFMA C-init bias (R9/R10: failures)
//  - s_setprio around MFMA clusters (R11: -5%; homogeneous waves, no role-split)
//  - skipping the dead layer-2 x-store (R12: -4%; breaks loop-tail scheduling)
// This file is the verified-green optimum (R8): post-add biases from global,
// single-buffer H2T @4096, pair-permuted QKV with dword XOR swizzle, fences at
// every type-punned LDS write->read boundary, FFN token loop fully unrolled.

namespace {

constexpr int kB = 262144;

// ws B-fragment set bases (1 set = 64 lanes x 8 bf16 = 1 KiB)
constexpr int SET_W1 = 0;     // (100,23)  NT=7  KS=1
constexpr int SET_W2 = 7;     // (300,100) NT=20 KS=4
constexpr int SET_W3 = 87;    // (20,300)  NT=2  KS=10
constexpr int SET_WOBS = 107; // (20,17)   NT=2  KS=1
constexpr int SET_WACT = 109; // (20,6)    NT=2  KS=1, k shifted +17
constexpr int SET_WQKV = 111; // 3 x (60,20)  NT=4 KS=1
constexpr int SET_WO = 123;   // 3 x (20,20)  NT=2 KS=1
constexpr int SET_WF1 = 129;  // 3 x (128,20) NT=8 KS=1
constexpr int SET_WF2 = 153;  // 3 x (20,128) NT=2 KS=4
constexpr int NSETS = 177;

// per-wave LDS arena (ushort units). Arena = 4992 ushorts (9984 B).
constexpr int AR = 4992;
// XA:  [3 tok][16 rows][pitch 40]  x (pair-permuted bf16); token0 doubles as oa staging
// QKV: [3 tok][16 rows][pitch 64]  qkv, dword-XOR-swizzled; o overwrites in place
// ACT: [16][pitch 136]             h1 / ffn hidden — ALIASES QKV (disjoint in time)
// H2T: [16][pitch 40]              W2->W3 staging (aliases QKV tok2 tail)
constexpr int QKVu = 1920; // ushort base
constexpr int ACTu = 1920;
constexpr int H2Tu = 4096;

__device__ __forceinline__ unsigned pk_bf16(float lo, float hi) {
    unsigned r;
    asm("v_cvt_pk_bf16_f32 %0, %1, %2" : "=v"(r) : "v"(lo), "v"(hi));
    return r;
}
__device__ __forceinline__ float bf2f(ushort_t h) {
    return __uint_as_float(((unsigned)h) << 16);
}
__device__ __forceinline__ float red16(float v) {
    v = DPP_ADD(v, 0xB1);   // quad_perm [1,0,3,2]  (xor 1)
    v = DPP_ADD(v, 0x4E);   // quad_perm [2,3,0,1]  (xor 2)
    v = DPP_ADD(v, 0x124);  // row_ror:4
    v = DPP_ADD(v, 0x128);  // row_ror:8
    return v;
}
// feature f (0..63) -> ushort slot in a pair-permuted 64-wide row (no swizzle)
__device__ __forceinline__ int fslot(int f) {
    return ((f >> 5) << 5) + ((f & 15) << 1) + ((f >> 4) & 1);
}
// swizzled ushort offset within a QKV row; sw = (row&7)<<2
__device__ __forceinline__ int qoff(int f, int sw) {
    int s = fslot(f);
    return (((s >> 1) ^ sw) << 1) | (s & 1);
}

// ---------------- weight prep: fp32 -> bf16 B-fragments (permuted k) --------
__global__ void prep_weights(const float* __restrict__ W1, const float* __restrict__ W2,
                             const float* __restrict__ W3, const float* __restrict__ Wobs,
                             const float* __restrict__ Wact, const float* __restrict__ Wqkv,
                             const float* __restrict__ Wo, const float* __restrict__ Wf1,
                             const float* __restrict__ Wf2, ushort_t* __restrict__ ws) {
    int s = blockIdx.x, lane = threadIdx.x;
    const float* src;
    int Nout, Kin, kshift = 0, nt, ks;
    if (s < SET_W2) { src = W1; Nout = 100; Kin = 23; nt = s; ks = 0; }
    else if (s < SET_W3) { int t = s - SET_W2; src = W2; Nout = 300; Kin = 100; nt = t >> 2; ks = t & 3; }
    else if (s < SET_WOBS) { int t = s - SET_W3; src = W3; Nout = 20; Kin = 300; nt = t / 10; ks = t % 10; }
    else if (s < SET_WACT) { int t = s - SET_WOBS; src = Wobs; Nout = 20; Kin = 17; nt = t; ks = 0; }
    else if (s < SET_WQKV) { int t = s - SET_WACT; src = Wact; Nout = 20; Kin = 6; kshift = 17; nt = t; ks = 0; }
    else if (s < SET_WO) { int t = s - SET_WQKV; src = Wqkv + (t >> 2) * 1200; Nout = 60; Kin = 20; nt = t & 3; ks = 0; }
    else if (s < SET_WF1) { int t = s - SET_WO; src = Wo + (t >> 1) * 400; Nout = 20; Kin = 20; nt = t & 1; ks = 0; }
    else if (s < SET_WF2) { int t = s - SET_WF1; src = Wf1 + (t >> 3) * 2560; Nout = 128; Kin = 20; nt = t & 7; ks = 0; }
    else { int t = s - SET_WF2; src = Wf2 + (t >> 3) * 2560; Nout = 20; Kin = 128; int r = t & 7; nt = r >> 2; ks = r & 3; }

    int n = nt * 16 + (lane & 15);
    ushort_t h[8];
#pragma unroll
    for (int j = 0; j < 8; ++j) {
        int m = (lane >> 4) * 8 + j;             // k-slot within 32-span
        int kw = (m >> 1) + ((m & 1) << 4);      // pair-permuted feature within span
        int k = ks * 32 + kw;
        float v = 0.f;
        if (n < Nout && k >= kshift && k < kshift + Kin) v = src[n * Kin + (k - kshift)];
        unsigned u = __float_as_uint(v);
        h[j] = (ushort_t)((u + 0x7FFFu + ((u >> 16) & 1u)) >> 16);
    }
    uint4 pk;
    pk.x = (unsigned)h[0] | ((unsigned)h[1] << 16);
    pk.y = (unsigned)h[2] | ((unsigned)h[3] << 16);
    pk.z = (unsigned)h[4] | ((unsigned)h[5] << 16);
    pk.w = (unsigned)h[6] | ((unsigned)h[7] << 16);
    ((uint4*)ws)[s * 64 + lane] = pk;
}

// LN over 20 valid cols; y1 cols (16+r16)>=20 are exact zeros; ga1/ba1 pre-masked
__device__ __forceinline__ void ln20(f32x4& y0, f32x4& y1, float ga0, float ba0,
                                     float ga1, float ba1) {
#pragma unroll
    for (int j = 0; j < 4; ++j) {
        float s = red16(y0[j] + y1[j]);
        float s2 = red16(y0[j] * y0[j] + y1[j] * y1[j]);
        float mean = s * 0.05f;
        float var = s2 * 0.05f - mean * mean;
        float r = rsqrtf(var + 1e-5f);
        y0[j] = (y0[j] - mean) * r * ga0 + ba0;
        y1[j] = (y1[j] - mean) * r * ga1 + ba1;
    }
}

__global__ __launch_bounds__(128, 4)
void oat_mfma12(const float* __restrict__ obs, const float* __restrict__ act,
                const float* __restrict__ b1, const float* __restrict__ b2,
                const float* __restrict__ b3, const float* __restrict__ bobs,
                const float* __restrict__ bact, const float* __restrict__ pos,
                const float* __restrict__ bqkv, const float* __restrict__ bo,
                const float* __restrict__ g1, const float* __restrict__ be1,
                const float* __restrict__ bf1, const float* __restrict__ bf2,
                const float* __restrict__ g2, const float* __restrict__ be2,
                const float* __restrict__ Wfc, const float* __restrict__ bfc,
                const ushort_t* __restrict__ wsb, float* __restrict__ out) {
    __shared__ __align__(16) ushort_t sm[2 * AR];
    const int lane = threadIdx.x & 63, wid = threadIdx.x >> 6;
    const int r16 = lane & 15, kb = lane >> 4;
    const int row0 = blockIdx.x * 32 + wid * 16;
    ushort_t* S = sm + wid * AR;
    unsigned* SW = (unsigned*)S;
    const bf16x8* Bw = (const bf16x8*)wsb;
    const f32x4 zero = {0.f, 0.f, 0.f, 0.f};

    // ---- P0: stage oa (32 features: obs 0..16, act 17..22, pad) ------------
#pragma unroll
    for (int it = 0; it < 4; ++it) {
        int idx = it * 64 + lane;
        int r = idx >> 4, d = idx & 15;
        int gr = row0 + r;
        float lo = obs[gr * 17 + d];
        float hi = (d == 0) ? obs[gr * 17 + 16] : ((d <= 6) ? act[gr * 6 + (d - 1)] : 0.f);
        SW[r * 20 + d] = pk_bf16(lo, hi);
    }
    LDS_FENCE();  // oa stores -> aOA read

    // ---- P1: W1 (h1) + obs/act projections ---------------------------------
    f32x4 xf[3][2]; // [token][nt]
    bf16x8 aOA = *(const bf16x8*)(S + r16 * 40 + kb * 8);
    f32x4 c1[7];
#pragma unroll
    for (int nt = 0; nt < 7; ++nt) c1[nt] = MFMA16(aOA, Bw[(SET_W1 + nt) * 64 + lane], zero);
#pragma unroll
    for (int nt = 0; nt < 2; ++nt) {
        f32x4 po = MFMA16(aOA, Bw[(SET_WOBS + nt) * 64 + lane], zero);
        f32x4 pa = MFMA16(aOA, Bw[(SET_WACT + nt) * 64 + lane], zero);
        int col = nt * 16 + r16;
        bool v = col < 20;
        float aO = v ? (bobs[col] + pos[20 + col]) : 0.f;
        float aA = v ? (bact[col] + pos[40 + col]) : 0.f;
#pragma unroll
        for (int j = 0; j < 4; ++j) { po[j] += aO; pa[j] += aA; }
        xf[1][nt] = po;
        xf[2][nt] = pa;
    }
    // pack h1 -> ACT (4 spans of 32 feats; span3 hi-half = zeros)
#pragma unroll
    for (int m = 0; m < 4; ++m) {
        int cA = m * 32 + r16, cBc = m * 32 + 16 + r16;
        float ba = (cA < 100) ? b1[cA] : 0.f;
        float bb = (m < 3 && cBc < 100) ? b1[cBc] : 0.f;
#pragma unroll
        for (int j = 0; j < 4; ++j) {
            float lo = fmaxf(c1[2 * m][j] + ba, 0.f);
            float hi = (m < 3) ? fmaxf(c1[2 * m + 1][j] + bb, 0.f) : 0.f;
            SW[960 + (kb * 4 + j) * 68 + m * 16 + r16] = pk_bf16(lo, hi);
        }
    }
    LDS_FENCE();  // ACT stores -> aH1 reads
    bf16x8 aH1[4];
#pragma unroll
    for (int ks = 0; ks < 4; ++ks)
        aH1[ks] = *(const bf16x8*)(S + ACTu + r16 * 136 + ks * 32 + kb * 8);

    // ---- P2: W2 -> relu -> W3 ----------------------------------------------
    f32x4 mo[2];
    mo[0] = zero; mo[1] = zero;
#pragma unroll 1
    for (int np = 0; np < 10; ++np) {
        f32x4 cs[2];
#pragma unroll
        for (int sub = 0; sub < 2; ++sub) {
            cs[sub] = zero;
#pragma unroll
            for (int ks = 0; ks < 4; ++ks)
                cs[sub] = MFMA16(aH1[ks], Bw[(SET_W2 + (np * 2 + sub) * 4 + ks) * 64 + lane], cs[sub]);
        }
        int c0 = np * 32 + r16, c1c = np * 32 + 16 + r16;
        float b20 = (c0 < 300) ? b2[c0] : 0.f;
        float b21 = (c1c < 300) ? b2[c1c] : 0.f;
        LDS_FENCE();  // prev iter's aH2 read (buffer reuse, WAR) -> these stores
#pragma unroll
        for (int j = 0; j < 4; ++j)
            SW[2048 + (kb * 4 + j) * 20 + r16] =
                pk_bf16(fmaxf(cs[0][j] + b20, 0.f), fmaxf(cs[1][j] + b21, 0.f));
        LDS_FENCE();  // H2T stores -> aH2 read
        bf16x8 aH2 = *(const bf16x8*)(S + H2Tu + r16 * 40 + kb * 8);
#pragma unroll
        for (int nt2 = 0; nt2 < 2; ++nt2)
            mo[nt2] = MFMA16(aH2, Bw[(SET_W3 + nt2 * 10 + np) * 64 + lane], mo[nt2]);
    }

    // ---- P3: stack + pos; store x for all tokens ----------------------------
#pragma unroll
    for (int nt = 0; nt < 2; ++nt) {
        int col = nt * 16 + r16;
        float a0 = (col < 20) ? (b3[col] + pos[col]) : 0.f;
        f32x4 tt = mo[nt];
#pragma unroll
        for (int j = 0; j < 4; ++j) tt[j] += a0;
        xf[0][nt] = tt;
    }
#pragma unroll
    for (int t = 0; t < 3; ++t)
#pragma unroll
        for (int j = 0; j < 4; ++j)
            SW[t * 320 + (kb * 4 + j) * 20 + r16] = pk_bf16(xf[t][0][j], xf[t][1][j]);

    // ---- attention lane-address prep (lane-only, layer-invariant) -----------
    const int ah = lane & 3, ar = lane >> 2;
    const int swA = (ar & 7) << 2;
    int adr_q[5], adr_k[5], adr_v[5];
#pragma unroll
    for (int d = 0; d < 5; ++d) {
        adr_q[d] = qoff(ah * 5 + d, swA);
        adr_k[d] = qoff(20 + ah * 5 + d, swA);
        adr_v[d] = qoff(40 + ah * 5 + d, swA);
    }

    // ---- P4: 3 encoder layers ------------------------------------------------
#pragma unroll 1
    for (int l = 0; l < 3; ++l) {
        // hoisted per-layer biases / LN params
        float bq[4];
#pragma unroll
        for (int nt = 0; nt < 4; ++nt) {
            int col = nt * 16 + r16;
            bq[nt] = (col < 60) ? bqkv[l * 60 + col] : 0.f;
        }
        float bo0 = bo[l * 20 + r16];
        float bo1 = (r16 < 4) ? bo[l * 20 + 16 + r16] : 0.f;
        float fb0 = bf2[l * 20 + r16];
        float fb1 = (r16 < 4) ? bf2[l * 20 + 16 + r16] : 0.f;
        float g1a = g1[l * 20 + r16], e1a = be1[l * 20 + r16];
        float g1b = (r16 < 4) ? g1[l * 20 + 16 + r16] : 0.f;
        float e1b = (r16 < 4) ? be1[l * 20 + 16 + r16] : 0.f;
        float g2a = g2[l * 20 + r16], e2a = be2[l * 20 + r16];
        float g2b = (r16 < 4) ? g2[l * 20 + 16 + r16] : 0.f;
        float e2b = (r16 < 4) ? be2[l * 20 + 16 + r16] : 0.f;

        LDS_FENCE();  // x stores (P3 / prev-layer FFN) -> aX reads; ACT WAR
        // -- QKV GEMM (B-frags loaded once, 12 MFMAs in one window) --
        {
            bf16x8 bwq[4];
#pragma unroll
            for (int nt = 0; nt < 4; ++nt) bwq[nt] = Bw[(SET_WQKV + l * 4 + nt) * 64 + lane];
#pragma unroll
            for (int t = 0; t < 3; ++t) {
                bf16x8 aX = *(const bf16x8*)(S + t * 640 + r16 * 40 + kb * 8);
                f32x4 cq[4];
#pragma unroll
                for (int nt = 0; nt < 4; ++nt) cq[nt] = MFMA16(aX, bwq[nt], zero);
#pragma unroll
                for (int j = 0; j < 4; ++j) {
                    int row = kb * 4 + j;
                    int rsw = (row & 7) << 2;
                    SW[960 + t * 512 + row * 32 + (r16 ^ rsw)] =
                        pk_bf16(cq[0][j] + bq[0], cq[1][j] + bq[1]);
                    SW[960 + t * 512 + row * 32 + ((16 + r16) ^ rsw)] =
                        pk_bf16(cq[2][j] + bq[2], cq[3][j] + bq[3]);
                }
            }
        }
        LDS_FENCE();  // QKV pack stores -> attention ushort reads

        // -- attention: lane = (row ar, head ah); o overwrites q slots --
        {
            const int qb = QKVu + ar * 64;
            float q[3][5], kk[3][5], vv[3][5];
#pragma unroll
            for (int s = 0; s < 3; ++s)
#pragma unroll
                for (int d = 0; d < 5; ++d) {
                    q[s][d] = bf2f(S[qb + s * 1024 + adr_q[d]]);
                    kk[s][d] = bf2f(S[qb + s * 1024 + adr_k[d]]);
                    vv[s][d] = bf2f(S[qb + s * 1024 + adr_v[d]]);
                }
            float o[3][5];
#pragma unroll
            for (int s = 0; s < 3; ++s) {
                float sc[3];
#pragma unroll
                for (int t2 = 0; t2 < 3; ++t2) {
                    float a = 0.f;
#pragma unroll
                    for (int d = 0; d < 5; ++d) a = fmaf(q[s][d], kk[t2][d], a);
                    sc[t2] = a * 0.44721359549995793f;
                }
                float m = fmaxf(sc[0], fmaxf(sc[1], sc[2]));
                float e0 = __expf(sc[0] - m), e1 = __expf(sc[1] - m), e2 = __expf(sc[2] - m);
                float inv = 1.f / (e0 + e1 + e2);
                e0 *= inv; e1 *= inv; e2 *= inv;
#pragma unroll
                for (int d = 0; d < 5; ++d)
                    o[s][d] = fmaf(e0, vv[0][d], fmaf(e1, vv[1][d], e2 * vv[2][d]));
            }
#pragma unroll
            for (int s = 0; s < 3; ++s)
#pragma unroll
                for (int d = 0; d < 5; ++d)
                    S[qb + s * 1024 + adr_q[d]] = (ushort_t)pk_bf16(o[s][d], o[s][d]);
        }
        LDS_FENCE();  // o stores -> aO reads

        // -- Wo + residual + LN1 for ALL tokens (then QKV region is dead) --
        {
            bf16x8 bw_o0 = Bw[(SET_WO + l * 2 + 0) * 64 + lane];
            bf16x8 bw_o1 = Bw[(SET_WO + l * 2 + 1) * 64 + lane];
            int rsw = (r16 & 7) << 2;
#pragma unroll
            for (int t = 0; t < 3; ++t) {
                bf16x8 aO = *(const bf16x8*)(S + QKVu + t * 1024 + r16 * 64 + (((kb * 4) ^ rsw) << 1));
                f32x4 cw0 = MFMA16(aO, bw_o0, zero);
                f32x4 cw1 = MFMA16(aO, bw_o1, zero);
                f32x4 y0 = xf[t][0], y1 = xf[t][1];
#pragma unroll
                for (int j = 0; j < 4; ++j) { y0[j] += cw0[j] + bo0; y1[j] += cw1[j] + bo1; }
                ln20(y0, y1, g1a, e1a, g1b, e1b);
                xf[t][0] = y0; xf[t][1] = y1;
#pragma unroll
                for (int j = 0; j < 4; ++j)
                    SW[t * 320 + (kb * 4 + j) * 20 + r16] = pk_bf16(y0[j], y1[j]);
            }
        }

        // -- FFN all tokens (hidden aliases dead QKV region), fully unrolled --
#pragma unroll
        for (int t = 0; t < 3; ++t) {
            LDS_FENCE();  // x stores -> aX read; prev-t aF reads (ACT WAR) -> stores
            bf16x8 aX = *(const bf16x8*)(S + t * 640 + r16 * 40 + kb * 8);
            // FFN1: pack hidden in span pairs
#pragma unroll
            for (int m = 0; m < 4; ++m) {
                bf16x8 bwa = Bw[(SET_WF1 + l * 8 + 2 * m) * 64 + lane];
                bf16x8 bwb = Bw[(SET_WF1 + l * 8 + 2 * m + 1) * 64 + lane];
                float f0 = bf1[l * 128 + m * 32 + r16];
                float f1 = bf1[l * 128 + m * 32 + 16 + r16];
                f32x4 ca = MFMA16(aX, bwa, zero);
                f32x4 cb = MFMA16(aX, bwb, zero);
#pragma unroll
                for (int j = 0; j < 4; ++j)
                    SW[960 + (kb * 4 + j) * 68 + m * 16 + r16] =
                        pk_bf16(fmaxf(ca[j] + f0, 0.f), fmaxf(cb[j] + f1, 0.f));
            }
            LDS_FENCE();  // ACT stores -> aF reads
            // FFN2
            f32x4 c2[2];
            c2[0] = zero; c2[1] = zero;
#pragma unroll
            for (int ks = 0; ks < 4; ++ks) {
                bf16x8 aF = *(const bf16x8*)(S + ACTu + r16 * 136 + ks * 32 + kb * 8);
                c2[0] = MFMA16(aF, Bw[(SET_WF2 + l * 8 + ks) * 64 + lane], c2[0]);
                c2[1] = MFMA16(aF, Bw[(SET_WF2 + l * 8 + 4 + ks) * 64 + lane], c2[1]);
            }
            f32x4 z0 = xf[t][0], z1 = xf[t][1];
#pragma unroll
            for (int j = 0; j < 4; ++j) { z0[j] += c2[0][j] + fb0; z1[j] += c2[1][j] + fb1; }
            ln20(z0, z1, g2a, e2a, g2b, e2b);
            xf[t][0] = z0; xf[t][1] = z1;
#pragma unroll
            for (int j = 0; j < 4; ++j)
                SW[t * 320 + (kb * 4 + j) * 20 + r16] = pk_bf16(z0[j], z1[j]);
        }
    }

    // ---- P5: head (B,60) @ Wfc^T + bfc --------------------------------------
    f32x4 p = zero;
#pragma unroll
    for (int t = 0; t < 3; ++t) {
        float w0 = Wfc[t * 20 + r16];
        float w1 = (r16 < 4) ? Wfc[t * 20 + 16 + r16] : 0.f;
#pragma unroll
        for (int j = 0; j < 4; ++j)
            p[j] = fmaf(xf[t][0][j], w0, fmaf(xf[t][1][j], w1, p[j]));
    }
#pragma unroll
    for (int j = 0; j < 4; ++j) p[j] = red16(p[j]);
    if (r16 < 4) {
        float v = (r16 == 0) ? p[0] : (r16 == 1) ? p[1] : (r16 == 2) ? p[2] : p[3];
        out[row0 + kb * 4 + r16] = v + bfc[0];
    }
}

} // namespace

extern "C" void kernel_launch(void* const* d_in, const int* in_sizes, int n_in,
                              void* d_out, int out_size, void* d_ws, size_t ws_size,
                              hipStream_t stream) {
    (void)in_sizes; (void)n_in; (void)out_size; (void)ws_size;
    const float* obs  = (const float*)d_in[0];
    const float* act  = (const float*)d_in[1];
    const float* W1   = (const float*)d_in[2];
    const float* b1   = (const float*)d_in[3];
    const float* W2   = (const float*)d_in[4];
    const float* b2   = (const float*)d_in[5];
    const float* W3   = (const float*)d_in[6];
    const float* b3   = (const float*)d_in[7];
    const float* Wobs = (const float*)d_in[8];
    const float* bobs = (const float*)d_in[9];
    const float* Wact = (const float*)d_in[10];
    const float* bact = (const float*)d_in[11];
    const float* pos  = (const float*)d_in[12];
    const float* Wqkv = (const float*)d_in[13];
    const float* bqkv = (const float*)d_in[14];
    const float* Wo   = (const float*)d_in[15];
    const float* bo   = (const float*)d_in[16];
    const float* g1   = (const float*)d_in[17];
    const float* be1  = (const float*)d_in[18];
    const float* Wf1  = (const float*)d_in[19];
    const float* bf1  = (const float*)d_in[20];
    const float* Wf2  = (const float*)d_in[21];
    const float* bf2  = (const float*)d_in[22];
    const float* g2   = (const float*)d_in[23];
    const float* be2  = (const float*)d_in[24];
    const float* Wfc  = (const float*)d_in[25];
    const float* bfc  = (const float*)d_in[26];

    ushort_t* wsb = (ushort_t*)d_ws;

    hipLaunchKernelGGL(prep_weights, dim3(NSETS), dim3(64), 0, stream,
                       W1, W2, W3, Wobs, Wact, Wqkv, Wo, Wf1, Wf2, wsb);
    hipLaunchKernelGGL(oat_mfma12, dim3(kB / 32), dim3(128), 0, stream,
                       obs, act, b1, b2, b3, bobs, bact, pos, bqkv, bo,
                       g1, be1, bf1, bf2, g2, be2, Wfc, bfc, wsb, (float*)d_out);
}